// Round 11
// baseline (588.943 us; speedup 1.0000x reference)
//
#include <hip/hip_runtime.h>

// Billeh column GLIF forward — persistent kernel, flag-vector barrier,
// publish-early protocol with quad-buffered spike masks.
//
// R10 post-mortem: the hierarchical RMW barrier (group chain -> top -> release
// -> poll) kept ~3 serialized MALL round-trips + RMW serialization on every
// step. This version replaces it:
//  - arrival  = ONE plain uncached store flags[bid] = t+1 (no RMW),
//  - wait     = leader wave parallel-loads all 196 flags, ballot(all >= t),
//  - publish-early: the flag is stored BEFORE Phase B, so by the time any
//    block polls target t, flags were set ~a full phase ago -> first check
//    succeeds in steady state (skew tolerated up to ~1 phase),
//  - quad-buffered masks msk[t&3]: a publisher of mask(t) can only conflict
//    with stagers of mask(t-4), whose completion its previous poll already
//    certified (flag t-1 implies iteration t-3 fully done).
// Everything else (register-resident edges, LDS mask+acc, fence-free relaxed
// atomics, contention-free CSR build) carried from R9/R10.

constexpr int RR  = 4;
constexpr int BS  = 1024;               // threads per block
constexpr int BKN = 512;                // neurons per block (bucket size)
constexpr int NCH = 512;                // partition chunks

// ---------------- pass 1: per-chunk bucket histogram (+ misc zeroing) ------
__global__ void count_kernel(const int* __restrict__ post, int* __restrict__ ghist,
                             unsigned long long* __restrict__ msk,
                             unsigned* __restrict__ flags,
                             int E, int CH, int NBK, int nmask4) {
    __shared__ int h[256];                       // NBK <= 256
    for (int i = threadIdx.x; i < NBK; i += blockDim.x) h[i] = 0;
    __syncthreads();
    const int b = blockIdx.x, lo = b * CH, hi = min(lo + CH, E);
    for (int e = lo + threadIdx.x; e < hi; e += blockDim.x)
        atomicAdd(&h[post[e] >> 9], 1);          // LDS atomic: block-local
    __syncthreads();
    for (int i = threadIdx.x; i < NBK; i += blockDim.x)
        ghist[i * NCH + b] = h[i];               // bucket-major
    int g = blockIdx.x * blockDim.x + threadIdx.x;
    int gs = gridDim.x * blockDim.x;
    for (int i = g; i < nmask4; i += gs) msk[i] = 0ull;
    for (int i = g; i < NBK; i += gs) flags[i] = 0u;
}

// ---------------- pass 2a: per-bucket exclusive scan over chunks -----------
__global__ void scanA_kernel(int* __restrict__ ghist, int* __restrict__ rtot,
                             int* __restrict__ ptot) {
    __shared__ int s[NCH];
    const int i = blockIdx.x, tid = threadIdx.x;
    int v = ghist[i * NCH + tid];
    s[tid] = v;
    __syncthreads();
    for (int off = 1; off < NCH; off <<= 1) {
        int t = (tid >= off) ? s[tid - off] : 0;
        __syncthreads();
        s[tid] += t;
        __syncthreads();
    }
    ghist[i * NCH + tid] = s[tid] - v;           // within-bucket exclusive
    if (tid == NCH - 1) {
        int tot = s[tid];
        rtot[i] = tot;
        ptot[i] = (tot + 3) & ~3;                // pad to x4 records
    }
}

// ---------------- pass 2b: scan padded totals -> bstart; zero pad slots ----
__global__ void scanB_kernel(const int* __restrict__ rtot, const int* __restrict__ ptot,
                             int* __restrict__ bstart,
                             unsigned* __restrict__ epack, float* __restrict__ ew,
                             int NBK) {
    __shared__ int s[256];
    const int tid = threadIdx.x;
    int v = (tid < NBK) ? ptot[tid] : 0;
    s[tid] = v;
    __syncthreads();
    for (int off = 1; off < 256; off <<= 1) {
        int t = (tid >= off) ? s[tid - off] : 0;
        __syncthreads();
        s[tid] += t;
        __syncthreads();
    }
    if (tid < NBK) bstart[tid] = s[tid] - v;
    if (tid == NBK - 1) bstart[NBK] = s[tid];
    __syncthreads();
    if (tid < NBK) {                              // zero the <=3 pad records
        int base = bstart[tid];
        for (int k = base + rtot[tid]; k < base + ptot[tid]; ++k) {
            epack[k] = 0u; ew[k] = 0.f;           // pre=0,w=0 -> harmless
        }
    }
}

// ---------------- pass 3: fill with block-local LDS cursors ----------------
// record: epack = pre(18b) | rc<<18 | lidx<<20 ; ew = weight
__global__ void fill_kernel(const int* __restrict__ pre, const int* __restrict__ post,
                            const int* __restrict__ rc, const float* __restrict__ w,
                            const int* __restrict__ ghist, const int* __restrict__ bstart,
                            unsigned* __restrict__ epack, float* __restrict__ ew,
                            int E, int CH, int NBK) {
    __shared__ int cur[256];
    const int b = blockIdx.x;
    for (int i = threadIdx.x; i < NBK; i += blockDim.x)
        cur[i] = bstart[i] + ghist[i * NCH + b];
    __syncthreads();
    const int lo = b * CH, hi = min(lo + CH, E);
    for (int e = lo + threadIdx.x; e < hi; e += blockDim.x) {
        int pn = post[e];
        int k = atomicAdd(&cur[pn >> 9], 1);     // LDS atomic: block-local
        epack[k] = (unsigned)pre[e] | ((unsigned)rc[e] << 18)
                 | ((unsigned)(pn & (BKN - 1)) << 20);
        ew[k] = w[e];
    }
}

// ---------------- persistent sim ----------------
__device__ __forceinline__ void test4(const uint4 pk, const float4 wv,
                                      const unsigned long long* smask,
                                      float* sacc) {
    unsigned a = pk.x & 0x3FFFFu, b = pk.y & 0x3FFFFu;
    unsigned c = pk.z & 0x3FFFFu, d = pk.w & 0x3FFFFu;
    if ((smask[a >> 6] >> (a & 63)) & 1ull) atomicAdd(&sacc[pk.x >> 18], wv.x);
    if ((smask[b >> 6] >> (b & 63)) & 1ull) atomicAdd(&sacc[pk.y >> 18], wv.y);
    if ((smask[c >> 6] >> (c & 63)) & 1ull) atomicAdd(&sacc[pk.z >> 18], wv.z);
    if ((smask[d >> 6] >> (d & 63)) & 1ull) atomicAdd(&sacc[pk.w >> 18], wv.w);
}

__global__ void __launch_bounds__(BS, 4)
sim_kernel(const float4* __restrict__ x_ext4,
           const float* __restrict__ v0,  const float* __restrict__ v_th,
           const float* __restrict__ v_rst, const float* __restrict__ t_rf,
           const float* __restrict__ decay, const float* __restrict__ curf,
           const float* __restrict__ e_l,
           const float2* __restrict__ aamps, const float2* __restrict__ adec,
           const float* __restrict__ syn_d4, const float* __restrict__ psc_i4,
           const uint4* __restrict__ epack4, const float4* __restrict__ ew4,
           const int* __restrict__ bstart,
           unsigned long long* __restrict__ msk,    // 4 buffers x nmask
           unsigned* __restrict__ flags,            // NBK progress flags
           float* __restrict__ out, int N, int nmask, int T)
{
    extern __shared__ unsigned long long sdyn[];
    unsigned long long* smask = sdyn;            // nmask u64 (12.5 KB)
    float* sacc = (float*)(sdyn + nmask);        // BKN*4 floats (8 KB)
    const int tid = threadIdx.x;
    const int n = blockIdx.x * BKN + tid;        // owner mapping: tid < BKN
    const bool own = (tid < BKN) && (n < N);
    const int nblk = (int)gridDim.x;

    // ---- per-neuron state + params: registers for the whole run ----
    float psc0 = 0.f, psc1 = 0.f, psc2 = 0.f, psc3 = 0.f;
    float pr0 = 0.f, pr1 = 0.f, pr2 = 0.f, pr3 = 0.f;
    float vv = 0.f, rr_ = 0.f, zz = 0.f, a0 = 0.f, a1 = 0.f;
    float vth = 1.f, dvr = 0.f, trf = 0.f, dec = 0.f, cf = 0.f, el = 0.f;
    float aa0 = 0.f, aa1 = 0.f, ad0 = 0.f, ad1 = 0.f;
    if (own) {
        vv  = v0[n];
        vth = v_th[n];  dvr = v_rst[n] - vth;
        trf = t_rf[n];  dec = decay[n];
        cf  = curf[n];  el  = e_l[n];
        float2 aa = aamps[n]; aa0 = aa.x; aa1 = aa.y;
        float2 ad = adec[n];  ad0 = ad.x; ad1 = ad.y;
    }
    const float sd0 = syn_d4[0], sd1 = syn_d4[1], sd2 = syn_d4[2], sd3 = syn_d4[3];
    const float pi0 = psc_i4[0], pi1 = psc_i4[1], pi2 = psc_i4[2], pi3 = psc_i4[3];

    // ---- preload this thread's edges into REGISTERS (constant across t) ----
    const int q_lo = bstart[blockIdx.x] >> 2;    // 4-aligned by construction
    const int q_hi = bstart[blockIdx.x + 1] >> 2;
    const int i0 = q_lo + tid, i1 = i0 + BS, i2 = i1 + BS, i3 = i2 + BS;
    const uint4 z4 = make_uint4(0u, 0u, 0u, 0u);
    const float4 zf = make_float4(0.f, 0.f, 0.f, 0.f);
    uint4  qa = (i0 < q_hi) ? epack4[i0] : z4;
    uint4  qb = (i1 < q_hi) ? epack4[i1] : z4;
    uint4  qc = (i2 < q_hi) ? epack4[i2] : z4;
    uint4  qd = (i3 < q_hi) ? epack4[i3] : z4;
    float4 wa = (i0 < q_hi) ? ew4[i0] : zf;
    float4 wb = (i1 < q_hi) ? ew4[i1] : zf;
    float4 wc = (i2 < q_hi) ? ew4[i2] : zf;
    float4 wd = (i3 < q_hi) ? ew4[i3] : zf;
    const bool overflow = (q_hi - q_lo) > 4 * BS;   // practically never

    // ---- prologue: zero LDS mask + accumulators; prefetch x(0) ----
    for (int i = tid; i < nmask; i += BS) smask[i] = 0ull;
    sacc[tid] = 0.f; sacc[tid + BS] = 0.f;
    float4 xt = own ? x_ext4[n] : zf;
    __syncthreads();

    for (int t = 0; t < T; ++t) {
        const bool lastT = (t + 1 >= T);

        // ======== Phase A: spike decision (OLD state only) ========
        float nz = 0.f;
        if (own) {
            float npc0 = psc0 * sd0 + sd0 * pr0;   // OLD psc_rise, DT=1
            float npc1 = psc1 * sd1 + sd1 * pr1;
            float npc2 = psc2 * sd2 + sd2 * pr2;
            float npc3 = psc3 * sd3 + sd3 * pr3;
            float in_cur = npc0 + npc1 + npc2 + npc3;
            float asum = a0 + a1;                // OLD asc sum
            float nv = dec * vv + cf * (in_cur + asum + el) + zz * dvr;
            nz = (nv > vth) ? 1.f : 0.f;
            if (rr_ > 0.f) nz = 0.f;             // refractory mask (OLD r)
            rr_ = fmaxf(rr_ - 1.f + nz * trf, 0.f);
            a0 = ad0 * a0 + zz * aa0;            // asc update uses OLD z
            a1 = ad1 * a1 + zz * aa1;
            psc0 = npc0; psc1 = npc1; psc2 = npc2; psc3 = npc3;
            vv = nv;
        }

        // publish mask(t) into msk[t&3] (uncached store; one per wave)
        unsigned long long bal = __ballot(nz > 0.f);
        if (!lastT) {
            if (own && (tid & 63) == 0)
                __hip_atomic_store(&msk[(size_t)(t & 3) * nmask + (n >> 6)], bal,
                                   __ATOMIC_RELAXED, __HIP_MEMORY_SCOPE_AGENT);
            asm volatile("s_waitcnt vmcnt(0)" ::: "memory");
        }
        __syncthreads();                          // S1: all publishes drained

        // arrival: ONE plain store (certifies mask(t) is globally visible)
        if (!lastT && tid == 0)
            __hip_atomic_store(&flags[blockIdx.x], (unsigned)(t + 1),
                               __ATOMIC_RELAXED, __HIP_MEMORY_SCOPE_AGENT);

        // wait for mask(t-1): leader wave parallel-polls all flags >= t.
        // Flags were set BEFORE the other blocks' Phase B (publish-early), so
        // in steady state the first check succeeds.
        int anyspk = 0;
        if (t > 0) {
            if (tid < 64) {
                const unsigned target = (unsigned)t;
                for (;;) {
                    unsigned f0 = (tid < nblk)
                        ? __hip_atomic_load(&flags[tid], __ATOMIC_RELAXED,
                                            __HIP_MEMORY_SCOPE_AGENT) : target;
                    unsigned f1 = (tid + 64 < nblk)
                        ? __hip_atomic_load(&flags[tid + 64], __ATOMIC_RELAXED,
                                            __HIP_MEMORY_SCOPE_AGENT) : target;
                    unsigned f2 = (tid + 128 < nblk)
                        ? __hip_atomic_load(&flags[tid + 128], __ATOMIC_RELAXED,
                                            __HIP_MEMORY_SCOPE_AGENT) : target;
                    unsigned f3 = (tid + 192 < nblk)
                        ? __hip_atomic_load(&flags[tid + 192], __ATOMIC_RELAXED,
                                            __HIP_MEMORY_SCOPE_AGENT) : target;
                    bool bad = (f0 < target) | (f1 < target) |
                               (f2 < target) | (f3 < target);
                    if (__ballot(bad) == 0ull) break;
                    __builtin_amdgcn_s_sleep(1);
                }
            }
            __syncthreads();                      // S3: released

            // stage mask(t-1) from msk[(t-1)&3] into LDS
            const unsigned long long* gm = msk + (size_t)((t - 1) & 3) * nmask;
            unsigned long long m0 = 0ull, m1 = 0ull;
            if (tid < nmask)
                m0 = __hip_atomic_load(&gm[tid], __ATOMIC_RELAXED,
                                       __HIP_MEMORY_SCOPE_AGENT);
            if (tid + BS < nmask)
                m1 = __hip_atomic_load(&gm[tid + BS], __ATOMIC_RELAXED,
                                       __HIP_MEMORY_SCOPE_AGENT);
            if (tid < nmask) smask[tid] = m0;
            if (tid + BS < nmask) smask[tid + BS] = m1;
            anyspk = __syncthreads_or((m0 | m1) != 0ull ? 1 : 0);   // S4
        }

        // ======== Phase B: edge phase vs mask(t-1) + psc_rise update ========
        if (anyspk) {
            test4(qa, wa, smask, sacc);
            test4(qb, wb, smask, sacc);
            test4(qc, wc, smask, sacc);
            test4(qd, wd, smask, sacc);
            if (overflow) {
                for (int q = q_lo + tid + 4 * BS; q < q_hi; q += BS)
                    test4(epack4[q], ew4[q], smask, sacc);
            }
        }
        __syncthreads();                          // S2: edge writes visible

        if (own) {
            float acc0 = sacc[tid * 4 + 0], acc1 = sacc[tid * 4 + 1];
            float acc2 = sacc[tid * 4 + 2], acc3 = sacc[tid * 4 + 3];
            sacc[tid * 4 + 0] = 0.f; sacc[tid * 4 + 1] = 0.f;  // re-zero own slots
            sacc[tid * 4 + 2] = 0.f; sacc[tid * 4 + 3] = 0.f;
            pr0 = pr0 * sd0 + (acc0 + xt.x) * pi0;   // new psc_rise
            pr1 = pr1 * sd1 + (acc1 + xt.y) * pi1;
            pr2 = pr2 * sd2 + (acc2 + xt.z) * pi2;
            pr3 = pr3 * sd3 + (acc3 + xt.w) * pi3;
            out[(size_t)t * N + n] = nz;
            zz = nz;
        }
        if (!lastT)
            xt = own ? x_ext4[(size_t)(t + 1) * N + n] : zf;
    }
}

// ---------------- launch ----------------
extern "C" void kernel_launch(void* const* d_in, const int* in_sizes, int n_in,
                              void* d_out, int out_size, void* d_ws, size_t ws_size,
                              hipStream_t stream) {
    const float* w_rec = (const float*)d_in[0];
    const float* x_ext = (const float*)d_in[1];
    const float* v0    = (const float*)d_in[2];
    const float* v_th  = (const float*)d_in[3];
    const float* v_rst = (const float*)d_in[4];
    const float* t_rf  = (const float*)d_in[5];
    const float* decay = (const float*)d_in[6];
    const float* curf  = (const float*)d_in[7];
    const float* e_l   = (const float*)d_in[8];
    const float* aamps = (const float*)d_in[9];
    const float* adec  = (const float*)d_in[10];
    const float* syn_d = (const float*)d_in[11];
    const float* psc_i = (const float*)d_in[12];
    const int*   pre   = (const int*)d_in[13];
    const int*   post  = (const int*)d_in[14];
    const int*   rc    = (const int*)d_in[15];

    const int E = in_sizes[0];
    const int N = in_sizes[2];            // B == 1
    const int T = in_sizes[1] / (N * RR);
    const int nmask = (N + 63) / 64;
    const int NBK = (N + BKN - 1) / BKN;  // buckets == sim blocks (196)
    const int CH  = (E + NCH - 1) / NCH;
    const int EP  = E + 4 * NBK;          // padded edge capacity

    // -------- workspace layout --------
    char* ws = (char*)d_ws;
    unsigned* epack  = (unsigned*)ws;                     ws += (size_t)EP * 4;
    float*    ew     = (float*)ws;                        ws += (size_t)EP * 4;
    unsigned long long* msk = (unsigned long long*)ws;    ws += (size_t)4 * nmask * 8;
    int* ghist       = (int*)ws;                          ws += (size_t)NBK * NCH * 4;
    int* rtot        = (int*)ws;                          ws += (size_t)NBK * 4;
    int* ptot        = (int*)ws;                          ws += (size_t)NBK * 4;
    int* bstart      = (int*)ws;                          ws += (size_t)(NBK + 1) * 4;
    unsigned* flags  = (unsigned*)ws;                     /* +NBK*4 */

    // -------- setup (4 dispatches, contention-free) --------
    count_kernel<<<NCH, 256, 0, stream>>>(post, ghist, msk, flags,
                                          E, CH, NBK, 4 * nmask);
    scanA_kernel<<<NBK, NCH, 0, stream>>>(ghist, rtot, ptot);
    scanB_kernel<<<1, 256, 0, stream>>>(rtot, ptot, bstart, epack, ew, NBK);
    fill_kernel<<<NCH, 256, 0, stream>>>(pre, post, rc, w_rec, ghist, bstart,
                                         epack, ew, E, CH, NBK);

    // -------- persistent sim: 196 blocks x 1024, 1 block/CU ----------------
    const size_t smbytes = (size_t)nmask * 8 + (size_t)BKN * RR * 4;  // ~20.5 KB
    sim_kernel<<<NBK, BS, smbytes, stream>>>(
        (const float4*)x_ext, v0, v_th, v_rst, t_rf, decay, curf, e_l,
        (const float2*)aamps, (const float2*)adec, syn_d, psc_i,
        (const uint4*)epack, (const float4*)ew, bstart, msk, flags,
        (float*)d_out, N, nmask, T);
}